// Round 5
// baseline (28070.093 us; speedup 1.0000x reference)
//
#include <hip/hip_runtime.h>

typedef unsigned short ushort_t;
typedef unsigned int uint_t;
typedef __bf16 bf16x8 __attribute__((ext_vector_type(8)));
typedef float f32x4 __attribute__((ext_vector_type(4)));

#define T_STEPS 512
#define REC_WGS 128
#define LDS_P 1032  // padded LDS row stride in bf16 elements

__device__ __forceinline__ ushort_t f2bf(float f) {
  union { float f; unsigned u; } v; v.f = f;
  unsigned r = (v.u + 0x7FFFu + ((v.u >> 16) & 1u)) >> 16;
  return (ushort_t)r;
}
__device__ __forceinline__ uint_t pack2(float a, float b) {
  return (uint_t)f2bf(a) | ((uint_t)f2bf(b) << 16);
}
__device__ __forceinline__ float sigf(float x) {
  return 1.0f / (1.0f + __expf(-x));
}

// ---------------------------------------------------------------------------
// fp32 -> bf16 conversion, vectorized (float4 in, ushort4 out), grid-stride
// ---------------------------------------------------------------------------
__global__ void __launch_bounds__(256) cvt_f32_bf16(
    const float* __restrict__ in, ushort_t* __restrict__ outp, int n4) {
  int i = blockIdx.x * 256 + threadIdx.x;
  const int stride = gridDim.x * 256;
  for (; i < n4; i += stride) {
    float4 v = ((const float4*)in)[i];
    ushort4 o;
    o.x = f2bf(v.x); o.y = f2bf(v.y); o.z = f2bf(v.z); o.w = f2bf(v.w);
    ((ushort4*)outp)[i] = o;
  }
}

// ---------------------------------------------------------------------------
// GEMM: out[m][n] = sum_k X[m][k] * Wm[n][k] + bi[n]
// X, Wm bf16; bi fp32; out bf16 (internal xg buffer).
// grid = dim3(M/128, 32). N=4096, K=1024. BM=BN=128, BK=64, 4 waves.
// ---------------------------------------------------------------------------
__global__ void __launch_bounds__(256, 1) gemm_xg(
    const ushort_t* __restrict__ X, const ushort_t* __restrict__ Wm,
    const float* __restrict__ bi, ushort_t* __restrict__ outp) {
  __shared__ char smem[65536];  // 2 buffers x (16KB A + 16KB B)
  const int tid = threadIdx.x;
  const int lane = tid & 63, w = tid >> 6;
  const int m0 = blockIdx.x * 128, n0 = blockIdx.y * 128;
  const int wr = w >> 1, wc = w & 1;
  const int lr = lane & 15, kg = lane >> 4;

  f32x4 acc[4][4] = {};

  auto stage = [&](int kt, int p) {
    const int ks = kt * 64;
    char* sA = smem + p * 32768;
    char* sB = sA + 16384;
#pragma unroll
    for (int i = 0; i < 4; ++i) {
      int wi = w * 4 + i;          // 0..15
      int e = wi * 64 + lane;      // 0..1023
      int row = e >> 3, pb = e & 7;
      int kb = pb ^ (row & 7);     // XOR swizzle applied on global src
      const ushort_t* gA = X + (size_t)(m0 + row) * 1024 + ks + kb * 8;
      __builtin_amdgcn_global_load_lds(
          (const __attribute__((address_space(1))) void*)gA,
          (__attribute__((address_space(3))) void*)(sA + wi * 1024), 16, 0, 0);
      const ushort_t* gB = Wm + (size_t)(n0 + row) * 1024 + ks + kb * 8;
      __builtin_amdgcn_global_load_lds(
          (const __attribute__((address_space(1))) void*)gB,
          (__attribute__((address_space(3))) void*)(sB + wi * 1024), 16, 0, 0);
    }
  };

  stage(0, 0);
  __syncthreads();
#pragma unroll 1
  for (int kt = 0; kt < 16; ++kt) {
    const int p = kt & 1;
    if (kt < 15) stage(kt + 1, p ^ 1);
    const char* sA = smem + p * 32768;
    const char* sB = sA + 16384;
#pragma unroll
    for (int k2 = 0; k2 < 2; ++k2) {
      bf16x8 af[4], bf[4];
#pragma unroll
      for (int mt = 0; mt < 4; ++mt) {
        int ar = wr * 64 + mt * 16 + lr;
        int kb = k2 * 4 + kg;
        af[mt] = *(const bf16x8*)(sA + ar * 128 + ((kb ^ (ar & 7)) << 4));
      }
#pragma unroll
      for (int nt = 0; nt < 4; ++nt) {
        int br = wc * 64 + nt * 16 + lr;
        int kb = k2 * 4 + kg;
        bf[nt] = *(const bf16x8*)(sB + br * 128 + ((kb ^ (br & 7)) << 4));
      }
#pragma unroll
      for (int mt = 0; mt < 4; ++mt)
#pragma unroll
        for (int nt = 0; nt < 4; ++nt)
          acc[mt][nt] = __builtin_amdgcn_mfma_f32_16x16x32_bf16(
              af[mt], bf[nt], acc[mt][nt], 0, 0, 0);
    }
    __syncthreads();
  }
#pragma unroll
  for (int nt = 0; nt < 4; ++nt) {
    int gc = n0 + wc * 64 + nt * 16 + lr;
    float bv = bi[gc];
#pragma unroll
    for (int mt = 0; mt < 4; ++mt) {
#pragma unroll
      for (int r = 0; r < 4; ++r) {
        int gr = m0 + wr * 64 + mt * 16 + kg * 4 + r;
        outp[(size_t)gr * 4096 + gc] = f2bf(acc[mt][nt][r] + bv);
      }
    }
  }
}

// ---------------------------------------------------------------------------
// Persistent recurrence for steps [t0, t0+nsteps). 128 WGs x 256 threads.
// WG wg owns hidden cols [wg*8, wg*8+8) x 4 gates (32 gate columns).
// R fp32 -> bf16 into LDS once. h recurrence via bf16 ping-pong hpp[2][32][1024].
// c carried fp32 in cstate across chunks. Outputs written fp32 to d_out.
// gates i,o,z,f:  c = c*f + z - i;  h = sig(c) - o.
// ---------------------------------------------------------------------------
__global__ void __launch_bounds__(256, 1) rec_kernel(
    const ushort_t* __restrict__ xg, const float* __restrict__ R,
    const float* __restrict__ bh, const float* __restrict__ h0l,
    const float* __restrict__ c0l, float* __restrict__ cstate,
    ushort_t* __restrict__ hpp, float* __restrict__ out_f,
    float* __restrict__ hfin, float* __restrict__ cfin,
    uint_t* __restrict__ flags, int t0, int nsteps, uint_t gen_base) {
  extern __shared__ char smem[];
  ushort_t* Rl = (ushort_t*)smem;                 // [32][LDS_P] bf16
  ushort_t* hl = (ushort_t*)(smem + 66048);       // [32][LDS_P] bf16
  float* gl = (float*)(smem + 132096);            // [32][32] f32

  const int tid = threadIdx.x;
  const int wg = blockIdx.x;
  const int j0 = wg * 8;
  const int lane = tid & 63, w = tid >> 6;
  const int mt16 = (w >> 1) << 4, nt16 = (w & 1) << 4;
  const int lr = lane & 15, kg = lane >> 4;
  const int b = tid >> 3, jj = tid & 7;

  // one-time: load+convert R slice. LDS col c: gate g=c>>3, hid j0+(c&7)
#pragma unroll 2
  for (int it = 0; it < 16; ++it) {
    int idx = it * 256 + tid;
    int c = idx >> 7, k8 = (idx & 127) * 8;
    int gr = (c >> 3) * 1024 + j0 + (c & 7);
    const float* src = R + (size_t)gr * 1024 + k8;
    float4 f0 = *(const float4*)src;
    float4 f1 = *(const float4*)(src + 4);
    uint4 o;
    o.x = pack2(f0.x, f0.y); o.y = pack2(f0.z, f0.w);
    o.z = pack2(f1.x, f1.y); o.w = pack2(f1.z, f1.w);
    *(uint4*)(Rl + c * LDS_P + k8) = o;
  }

  float bhv[4];
#pragma unroll
  for (int g = 0; g < 4; ++g) bhv[g] = bh[g * 1024 + j0 + jj];
  const int cidx = b * 1024 + j0 + jj;
  float c_st = (t0 == 0) ? c0l[cidx] : cstate[cidx];

  for (int tl = 0; tl < nsteps; ++tl) {
    const int t = t0 + tl;
    if (t == 0) {
      // stage+convert initial h from fp32 h0
#pragma unroll 2
      for (int it = 0; it < 16; ++it) {
        int idx = it * 256 + tid;
        int r = idx >> 7, k8 = (idx & 127) * 8;
        const float* src = h0l + (size_t)r * 1024 + k8;
        float4 f0 = *(const float4*)src;
        float4 f1 = *(const float4*)(src + 4);
        uint4 o;
        o.x = pack2(f0.x, f0.y); o.y = pack2(f0.z, f0.w);
        o.z = pack2(f1.x, f1.y); o.w = pack2(f1.z, f1.w);
        *(uint4*)(hl + r * LDS_P + k8) = o;
      }
    } else {
      const ushort_t* hsrc = hpp + (size_t)((t - 1) & 1) * 32768;
#pragma unroll 4
      for (int it = 0; it < 16; ++it) {
        int idx = it * 256 + tid;
        int r = idx >> 7, k8 = (idx & 127) * 8;
        uint4 v = *(const uint4*)(hsrc + (size_t)r * 1024 + k8);
        *(uint4*)(hl + r * LDS_P + k8) = v;
      }
    }
    float xgv[4];
    const size_t xbase = ((size_t)tl * 32 + b) * 4096 + j0 + jj;
#pragma unroll
    for (int g = 0; g < 4; ++g) {
      union { unsigned u; float f; } cv;
      cv.u = ((unsigned)xg[xbase + (size_t)g * 1024]) << 16;
      xgv[g] = cv.f;
    }
    __syncthreads();

    f32x4 acc = {0.f, 0.f, 0.f, 0.f};
#pragma unroll 8
    for (int kt = 0; kt < 32; ++kt) {
      int k = kt * 32 + kg * 8;
      bf16x8 a = *(const bf16x8*)(hl + (mt16 + lr) * LDS_P + k);
      bf16x8 bb = *(const bf16x8*)(Rl + (nt16 + lr) * LDS_P + k);
      acc = __builtin_amdgcn_mfma_f32_16x16x32_bf16(a, bb, acc, 0, 0, 0);
    }
#pragma unroll
    for (int r = 0; r < 4; ++r)
      gl[(mt16 + kg * 4 + r) * 32 + nt16 + lr] = acc[r];
    __syncthreads();

    float pre0 = gl[b * 32 + 0 * 8 + jj] + xgv[0] + bhv[0];
    float pre1 = gl[b * 32 + 1 * 8 + jj] + xgv[1] + bhv[1];
    float pre2 = gl[b * 32 + 2 * 8 + jj] + xgv[2] + bhv[2];
    float pre3 = gl[b * 32 + 3 * 8 + jj] + xgv[3] + bhv[3];
    float ig = sigf(pre0), og = sigf(pre1), zg = sigf(pre2), fg = sigf(pre3);
    c_st = c_st * fg + zg - ig;
    float hv = sigf(c_st) - og;
    out_f[(size_t)t * 32768 + cidx] = hv;            // fp32 output
    hpp[(size_t)(t & 1) * 32768 + cidx] = f2bf(hv);  // bf16 recurrence carry
    if (t == T_STEPS - 1) {
      hfin[cidx] = hv;
      cfin[cidx] = c_st;
    }

    if (tl < nsteps - 1) {
      const uint_t gen1 = gen_base + (uint_t)tl + 1u;
      __threadfence();       // release
      __syncthreads();
      if (tid == 0) {
        __hip_atomic_store(&flags[wg], gen1, __ATOMIC_RELEASE,
                           __HIP_MEMORY_SCOPE_AGENT);
      }
      if (tid < REC_WGS) {
        while (__hip_atomic_load(&flags[tid], __ATOMIC_ACQUIRE,
                                 __HIP_MEMORY_SCOPE_AGENT) < gen1) {
          __builtin_amdgcn_s_sleep(1);
        }
      }
      __syncthreads();
      __threadfence();       // acquire
    }
  }
  cstate[cidx] = c_st;
}

// ---------------------------------------------------------------------------
extern "C" void kernel_launch(void* const* d_in, const int* in_sizes, int n_in,
                              void* d_out, int out_size, void* d_ws,
                              size_t ws_size, hipStream_t stream) {
  (void)in_sizes; (void)n_in; (void)out_size;
  const float* x = (const float*)d_in[0];
  const float* h0 = (const float*)d_in[1];
  const float* c0 = (const float*)d_in[2];
  const float* Ws[2] = {(const float*)d_in[3], (const float*)d_in[7]};
  const float* Rs[2] = {(const float*)d_in[4], (const float*)d_in[8]};
  const float* bis[2] = {(const float*)d_in[5], (const float*)d_in[9]};
  const float* bhs[2] = {(const float*)d_in[6], (const float*)d_in[10]};
  float* outp = (float*)d_out;

  // ws: Wbf(8MB) + xbf(T_CH*64KB) + xg(T_CH*256KB) + hpp(128KB) + cstate(128KB) + flags
  int T_CH = 512;
  while (T_CH > 8 &&
         8388608ull + (size_t)T_CH * (65536 + 262144) + 262144 + 4096 > ws_size)
    T_CH >>= 1;

  char* ws = (char*)d_ws;
  ushort_t* Wbf = (ushort_t*)ws;                              // [4096][1024] bf16
  ushort_t* xbf = (ushort_t*)(ws + 8388608);                  // chunk A, bf16
  ushort_t* xgb = (ushort_t*)(ws + 8388608 + (size_t)T_CH * 65536);
  ushort_t* hpp = (ushort_t*)((char*)xgb + (size_t)T_CH * 262144);  // [2][32][1024]
  float* cstate = (float*)((char*)hpp + 131072);              // [32][1024] f32
  uint_t* flags = (uint_t*)((char*)cstate + 131072);          // [128]

  const int REC_LDS = 2 * (32 * LDS_P * 2) + 32 * 32 * 4;  // 136192 B
  (void)hipFuncSetAttribute((const void*)rec_kernel,
                            hipFuncAttributeMaxDynamicSharedMemorySize,
                            REC_LDS);
  (void)hipMemsetAsync(flags, 0, REC_WGS * sizeof(uint_t), stream);

  float* hfin0 = outp + 16777216;
  float* hfin1 = hfin0 + 32768;
  float* cfin0 = hfin1 + 32768;
  float* cfin1 = cfin0 + 32768;

  const int xn4 = T_CH * 8192;  // chunk elements / 4

  for (int layer = 0; layer < 2; ++layer) {
    const float* h0l = h0 + layer * 32768;
    const float* c0l = c0 + layer * 32768;
    float* hfin = layer ? hfin1 : hfin0;
    float* cfin = layer ? cfin1 : cfin0;
    // convert layer weights W -> bf16 (4096x1024)
    cvt_f32_bf16<<<dim3(1024), dim3(256), 0, stream>>>(Ws[layer], Wbf, 1048576);
    for (int t0 = 0; t0 < T_STEPS; t0 += T_CH) {
      // layer 0 reads x; layer 1 reads layer-0 h (fp32, still in d_out rows >= t0)
      const float* Xin = layer ? (outp + (size_t)t0 * 32768)
                               : (x + (size_t)t0 * 32768);
      cvt_f32_bf16<<<dim3(2048), dim3(256), 0, stream>>>(Xin, xbf, xn4);
      gemm_xg<<<dim3(T_CH / 4, 32), dim3(256), 0, stream>>>(
          xbf, Wbf, bis[layer], xgb);
      // rec overwrites d_out rows [t0, t0+T_CH) with this layer's h (fp32)
      rec_kernel<<<dim3(REC_WGS), dim3(256), REC_LDS, stream>>>(
          xgb, Rs[layer], bhs[layer], h0l, c0l, cstate, hpp, outp, hfin, cfin,
          flags, t0, T_CH, (uint_t)(layer * T_STEPS + t0));
    }
  }
}

// Round 6
// 6904.453 us; speedup vs baseline: 4.0655x; 4.0655x over previous
//
#include <hip/hip_runtime.h>

typedef unsigned short ushort_t;
typedef unsigned int uint_t;
typedef unsigned long long u64_t;
typedef __bf16 bf16x8 __attribute__((ext_vector_type(8)));
typedef float f32x4 __attribute__((ext_vector_type(4)));

#define T_STEPS 512
#define REC_WGS 128
#define LDS_P 1032  // padded LDS row stride in bf16 elements
#define GL_P 33     // padded gate-tile stride in f32 (bank-conflict fix)

__device__ __forceinline__ ushort_t f2bf(float f) {
  union { float f; unsigned u; } v; v.f = f;
  unsigned r = (v.u + 0x7FFFu + ((v.u >> 16) & 1u)) >> 16;
  return (ushort_t)r;
}
__device__ __forceinline__ uint_t pack2(float a, float b) {
  return (uint_t)f2bf(a) | ((uint_t)f2bf(b) << 16);
}
__device__ __forceinline__ float sigf(float x) {
  return 1.0f / (1.0f + __expf(-x));
}

// ---------------------------------------------------------------------------
// fp32 -> bf16 conversion, vectorized (float4 in, ushort4 out), grid-stride
// ---------------------------------------------------------------------------
__global__ void __launch_bounds__(256) cvt_f32_bf16(
    const float* __restrict__ in, ushort_t* __restrict__ outp, int n4) {
  int i = blockIdx.x * 256 + threadIdx.x;
  const int stride = gridDim.x * 256;
  for (; i < n4; i += stride) {
    float4 v = ((const float4*)in)[i];
    ushort4 o;
    o.x = f2bf(v.x); o.y = f2bf(v.y); o.z = f2bf(v.z); o.w = f2bf(v.w);
    ((ushort4*)outp)[i] = o;
  }
}

// ---------------------------------------------------------------------------
// GEMM: out[m][n] = sum_k X[m][k] * Wm[n][k] + bi[n]
// X, Wm bf16; bi fp32; out bf16 (internal xg buffer).
// grid = dim3(M/128, 32). N=4096, K=1024. BM=BN=128, BK=64, 4 waves.
// ---------------------------------------------------------------------------
__global__ void __launch_bounds__(256, 1) gemm_xg(
    const ushort_t* __restrict__ X, const ushort_t* __restrict__ Wm,
    const float* __restrict__ bi, ushort_t* __restrict__ outp) {
  __shared__ char smem[65536];  // 2 buffers x (16KB A + 16KB B)
  const int tid = threadIdx.x;
  const int lane = tid & 63, w = tid >> 6;
  const int m0 = blockIdx.x * 128, n0 = blockIdx.y * 128;
  const int wr = w >> 1, wc = w & 1;
  const int lr = lane & 15, kg = lane >> 4;

  f32x4 acc[4][4] = {};

  auto stage = [&](int kt, int p) {
    const int ks = kt * 64;
    char* sA = smem + p * 32768;
    char* sB = sA + 16384;
#pragma unroll
    for (int i = 0; i < 4; ++i) {
      int wi = w * 4 + i;          // 0..15
      int e = wi * 64 + lane;      // 0..1023
      int row = e >> 3, pb = e & 7;
      int kb = pb ^ (row & 7);     // XOR swizzle applied on global src
      const ushort_t* gA = X + (size_t)(m0 + row) * 1024 + ks + kb * 8;
      __builtin_amdgcn_global_load_lds(
          (const __attribute__((address_space(1))) void*)gA,
          (__attribute__((address_space(3))) void*)(sA + wi * 1024), 16, 0, 0);
      const ushort_t* gB = Wm + (size_t)(n0 + row) * 1024 + ks + kb * 8;
      __builtin_amdgcn_global_load_lds(
          (const __attribute__((address_space(1))) void*)gB,
          (__attribute__((address_space(3))) void*)(sB + wi * 1024), 16, 0, 0);
    }
  };

  stage(0, 0);
  __syncthreads();
#pragma unroll 1
  for (int kt = 0; kt < 16; ++kt) {
    const int p = kt & 1;
    if (kt < 15) stage(kt + 1, p ^ 1);
    const char* sA = smem + p * 32768;
    const char* sB = sA + 16384;
#pragma unroll
    for (int k2 = 0; k2 < 2; ++k2) {
      bf16x8 af[4], bf[4];
#pragma unroll
      for (int mt = 0; mt < 4; ++mt) {
        int ar = wr * 64 + mt * 16 + lr;
        int kb = k2 * 4 + kg;
        af[mt] = *(const bf16x8*)(sA + ar * 128 + ((kb ^ (ar & 7)) << 4));
      }
#pragma unroll
      for (int nt = 0; nt < 4; ++nt) {
        int br = wc * 64 + nt * 16 + lr;
        int kb = k2 * 4 + kg;
        bf[nt] = *(const bf16x8*)(sB + br * 128 + ((kb ^ (br & 7)) << 4));
      }
#pragma unroll
      for (int mt = 0; mt < 4; ++mt)
#pragma unroll
        for (int nt = 0; nt < 4; ++nt)
          acc[mt][nt] = __builtin_amdgcn_mfma_f32_16x16x32_bf16(
              af[mt], bf[nt], acc[mt][nt], 0, 0, 0);
    }
    __syncthreads();
  }
#pragma unroll
  for (int nt = 0; nt < 4; ++nt) {
    int gc = n0 + wc * 64 + nt * 16 + lr;
    float bv = bi[gc];
#pragma unroll
    for (int mt = 0; mt < 4; ++mt) {
#pragma unroll
      for (int r = 0; r < 4; ++r) {
        int gr = m0 + wr * 64 + mt * 16 + kg * 4 + r;
        outp[(size_t)gr * 4096 + gc] = f2bf(acc[mt][nt][r] + bv);
      }
    }
  }
}

// ---------------------------------------------------------------------------
// Persistent recurrence for steps [t0, t0+nsteps). 128 WGs x 256 threads.
// Cross-WG h exchange via L3-coherent (sc0 sc1) loads/stores -- no cache-wide
// fences. Flags: relaxed agent atomics; ordering = vmcnt(0) drain before flag.
// gates i,o,z,f:  c = c*f + z - i;  h = sig(c) - o.
// ---------------------------------------------------------------------------
__global__ void __launch_bounds__(256, 1) rec_kernel(
    const ushort_t* __restrict__ xg, const float* __restrict__ R,
    const float* __restrict__ bh, const float* __restrict__ h0l,
    const float* __restrict__ c0l, float* __restrict__ cstate,
    ushort_t* __restrict__ hpp, float* __restrict__ out_f,
    float* __restrict__ hfin, float* __restrict__ cfin,
    uint_t* __restrict__ flags, int t0, int nsteps, uint_t gen_base) {
  extern __shared__ char smem[];
  ushort_t* Rl = (ushort_t*)smem;                 // [32][LDS_P] bf16
  ushort_t* hl = (ushort_t*)(smem + 66048);       // [32][LDS_P] bf16
  float* gl = (float*)(smem + 132096);            // [32][GL_P] f32

  const int tid = threadIdx.x;
  const int wg = blockIdx.x;
  const int j0 = wg * 8;
  const int lane = tid & 63, w = tid >> 6;
  const int mt16 = (w >> 1) << 4, nt16 = (w & 1) << 4;
  const int lr = lane & 15, kg = lane >> 4;
  const int b = tid >> 3, jj = tid & 7;
  uint_t* hpp32 = (uint_t*)hpp;

  // one-time: load+convert R slice. LDS col c: gate g=c>>3, hid j0+(c&7)
#pragma unroll 2
  for (int it = 0; it < 16; ++it) {
    int idx = it * 256 + tid;
    int c = idx >> 7, k8 = (idx & 127) * 8;
    int gr = (c >> 3) * 1024 + j0 + (c & 7);
    const float* src = R + (size_t)gr * 1024 + k8;
    float4 f0 = *(const float4*)src;
    float4 f1 = *(const float4*)(src + 4);
    uint4 o;
    o.x = pack2(f0.x, f0.y); o.y = pack2(f0.z, f0.w);
    o.z = pack2(f1.x, f1.y); o.w = pack2(f1.z, f1.w);
    *(uint4*)(Rl + c * LDS_P + k8) = o;
  }

  float bhv[4];
#pragma unroll
  for (int g = 0; g < 4; ++g) bhv[g] = bh[g * 1024 + j0 + jj];
  const int cidx = b * 1024 + j0 + jj;
  float c_st = (t0 == 0) ? c0l[cidx] : cstate[cidx];

  for (int tl = 0; tl < nsteps; ++tl) {
    const int t = t0 + tl;
    if (t == 0) {
      // stage+convert initial h from fp32 h0 (normal loads; first launch only)
#pragma unroll 2
      for (int it = 0; it < 16; ++it) {
        int idx = it * 256 + tid;
        int r = idx >> 7, k8 = (idx & 127) * 8;
        const float* src = h0l + (size_t)r * 1024 + k8;
        float4 f0 = *(const float4*)src;
        float4 f1 = *(const float4*)(src + 4);
        uint4 o;
        o.x = pack2(f0.x, f0.y); o.y = pack2(f0.z, f0.w);
        o.z = pack2(f1.x, f1.y); o.w = pack2(f1.z, f1.w);
        *(uint4*)(hl + r * LDS_P + k8) = o;
      }
    } else {
      // stage h(t-1): L3-coherent loads, all 32 in flight, one vmcnt drain.
      // row = it (0..31), elems tid*4..tid*4+3
      const u64_t* hsrc = (const u64_t*)hpp + ((size_t)((t - 1) & 1) << 13);
      u64_t hv64[32];
#pragma unroll
      for (int it = 0; it < 32; ++it) {
        asm volatile("global_load_dwordx2 %0, %1, off sc0 sc1"
                     : "=v"(hv64[it])
                     : "v"(hsrc + it * 256 + tid));
      }
      asm volatile("s_waitcnt vmcnt(0)" ::: "memory");
#pragma unroll
      for (int it = 0; it < 32; ++it)
        *(u64_t*)(hl + it * LDS_P + tid * 4) = hv64[it];
    }
    float xgv[4];
    const size_t xbase = ((size_t)tl * 32 + b) * 4096 + j0 + jj;
#pragma unroll
    for (int g = 0; g < 4; ++g) {
      union { unsigned u; float f; } cv;
      cv.u = ((unsigned)xg[xbase + (size_t)g * 1024]) << 16;
      xgv[g] = cv.f;
    }
    __syncthreads();

    f32x4 acc = {0.f, 0.f, 0.f, 0.f};
#pragma unroll 8
    for (int kt = 0; kt < 32; ++kt) {
      int k = kt * 32 + kg * 8;
      bf16x8 a = *(const bf16x8*)(hl + (mt16 + lr) * LDS_P + k);
      bf16x8 bb = *(const bf16x8*)(Rl + (nt16 + lr) * LDS_P + k);
      acc = __builtin_amdgcn_mfma_f32_16x16x32_bf16(a, bb, acc, 0, 0, 0);
    }
#pragma unroll
    for (int r = 0; r < 4; ++r)
      gl[(mt16 + kg * 4 + r) * GL_P + nt16 + lr] = acc[r];
    __syncthreads();

    float pre0 = gl[b * GL_P + 0 * 8 + jj] + xgv[0] + bhv[0];
    float pre1 = gl[b * GL_P + 1 * 8 + jj] + xgv[1] + bhv[1];
    float pre2 = gl[b * GL_P + 2 * 8 + jj] + xgv[2] + bhv[2];
    float pre3 = gl[b * GL_P + 3 * 8 + jj] + xgv[3] + bhv[3];
    float ig = sigf(pre0), og = sigf(pre1), zg = sigf(pre2), fg = sigf(pre3);
    c_st = c_st * fg + zg - ig;
    float hv = sigf(c_st) - og;
    out_f[(size_t)t * 32768 + cidx] = hv;            // fp32 output
    if (t == T_STEPS - 1) {
      hfin[cidx] = hv;
      cfin[cidx] = c_st;
    }

    // publish h(t): pack 2 bf16 per dword via shfl, L3-coherent store
    ushort_t hb = f2bf(hv);
    int partner = __shfl_down((int)hb, 1, 64);
    if ((tid & 1) == 0) {
      uint_t packed = (uint_t)hb | (((uint_t)(unsigned short)partner) << 16);
      uint_t* dst = hpp32 + (((t & 1) << 14) + (cidx >> 1));
      asm volatile("global_store_dword %0, %1, off sc0 sc1"
                   :: "v"(dst), "v"(packed) : "memory");
    }

    if (tl < nsteps - 1) {
      const uint_t gen1 = gen_base + (uint_t)tl + 1u;
      // drain own h stores (asm stores are untracked by compiler waitcnt)
      asm volatile("s_waitcnt vmcnt(0)" ::: "memory");
      __syncthreads();
      if (tid == 0) {
        __hip_atomic_store(&flags[wg], gen1, __ATOMIC_RELAXED,
                           __HIP_MEMORY_SCOPE_AGENT);
      }
      if (tid < REC_WGS) {
        while (__hip_atomic_load(&flags[tid], __ATOMIC_RELAXED,
                                 __HIP_MEMORY_SCOPE_AGENT) < gen1) {
          __builtin_amdgcn_s_sleep(1);
        }
      }
      __syncthreads();
      asm volatile("" ::: "memory");  // compiler barrier: no hoisting of h loads
    }
  }
  cstate[cidx] = c_st;
}

// ---------------------------------------------------------------------------
extern "C" void kernel_launch(void* const* d_in, const int* in_sizes, int n_in,
                              void* d_out, int out_size, void* d_ws,
                              size_t ws_size, hipStream_t stream) {
  (void)in_sizes; (void)n_in; (void)out_size;
  const float* x = (const float*)d_in[0];
  const float* h0 = (const float*)d_in[1];
  const float* c0 = (const float*)d_in[2];
  const float* Ws[2] = {(const float*)d_in[3], (const float*)d_in[7]};
  const float* Rs[2] = {(const float*)d_in[4], (const float*)d_in[8]};
  const float* bis[2] = {(const float*)d_in[5], (const float*)d_in[9]};
  const float* bhs[2] = {(const float*)d_in[6], (const float*)d_in[10]};
  float* outp = (float*)d_out;

  // ws: Wbf(8MB) + xbf(T_CH*64KB) + xg(T_CH*256KB) + hpp(128KB) + cstate(128KB) + flags
  int T_CH = 512;
  while (T_CH > 8 &&
         8388608ull + (size_t)T_CH * (65536 + 262144) + 262144 + 4096 > ws_size)
    T_CH >>= 1;

  char* ws = (char*)d_ws;
  ushort_t* Wbf = (ushort_t*)ws;                              // [4096][1024] bf16
  ushort_t* xbf = (ushort_t*)(ws + 8388608);                  // chunk A, bf16
  ushort_t* xgb = (ushort_t*)(ws + 8388608 + (size_t)T_CH * 65536);
  ushort_t* hpp = (ushort_t*)((char*)xgb + (size_t)T_CH * 262144);  // [2][32][1024]
  float* cstate = (float*)((char*)hpp + 131072);              // [32][1024] f32
  uint_t* flags = (uint_t*)((char*)cstate + 131072);          // [128]

  const int REC_LDS = 2 * (32 * LDS_P * 2) + 32 * GL_P * 4;  // 136320 B
  (void)hipFuncSetAttribute((const void*)rec_kernel,
                            hipFuncAttributeMaxDynamicSharedMemorySize,
                            REC_LDS);
  (void)hipMemsetAsync(flags, 0, REC_WGS * sizeof(uint_t), stream);

  float* hfin0 = outp + 16777216;
  float* hfin1 = hfin0 + 32768;
  float* cfin0 = hfin1 + 32768;
  float* cfin1 = cfin0 + 32768;

  const int xn4 = T_CH * 8192;  // chunk elements / 4

  for (int layer = 0; layer < 2; ++layer) {
    const float* h0l = h0 + layer * 32768;
    const float* c0l = c0 + layer * 32768;
    float* hfin = layer ? hfin1 : hfin0;
    float* cfin = layer ? cfin1 : cfin0;
    // convert layer weights W -> bf16 (4096x1024)
    cvt_f32_bf16<<<dim3(1024), dim3(256), 0, stream>>>(Ws[layer], Wbf, 1048576);
    for (int t0 = 0; t0 < T_STEPS; t0 += T_CH) {
      // layer 0 reads x; layer 1 reads layer-0 h (fp32, still in d_out rows >= t0)
      const float* Xin = layer ? (outp + (size_t)t0 * 32768)
                               : (x + (size_t)t0 * 32768);
      cvt_f32_bf16<<<dim3(2048), dim3(256), 0, stream>>>(Xin, xbf, xn4);
      gemm_xg<<<dim3(T_CH / 4, 32), dim3(256), 0, stream>>>(
          xbf, Wbf, bis[layer], xgb);
      // rec overwrites d_out rows [t0, t0+T_CH) with this layer's h (fp32)
      rec_kernel<<<dim3(REC_WGS), dim3(256), REC_LDS, stream>>>(
          xgb, Rs[layer], bhs[layer], h0l, c0l, cstate, hpp, outp, hfin, cfin,
          flags, t0, T_CH, (uint_t)(layer * T_STEPS + t0));
    }
  }
}